// Round 5
// baseline (178.412 us; speedup 1.0000x reference)
//
#include <hip/hip_runtime.h>

constexpr int NC = 32;    // channels C
constexpr int NH = 8;     // heads
constexpr int NS = 128;   // s
constexpr int NI = 256;   // i (q rows)
constexpr int NJ = 256;   // j (kv rows)
constexpr float LN_EPS = 1e-5f;
constexpr float QSCALE = 0.17677669529663687f;   // C^-0.5
constexpr float LOG2E  = 1.4426950408889634f;

typedef __bf16 bf16x8 __attribute__((ext_vector_type(8)));
typedef __bf16 bf16x2 __attribute__((ext_vector_type(2)));
typedef float floatx4 __attribute__((ext_vector_type(4)));

__device__ __forceinline__ float fexp2(float x) {
#if __has_builtin(__builtin_amdgcn_exp2f)
    return __builtin_amdgcn_exp2f(x);
#else
    return exp2f(x);
#endif
}
__device__ __forceinline__ float frcp(float x) {
#if __has_builtin(__builtin_amdgcn_rcpf)
    return __builtin_amdgcn_rcpf(x);
#else
    return 1.0f / x;
#endif
}
// HW bf16 pack (v_cvt_pk_bf16_f32 on gfx950), RNE
__device__ __forceinline__ unsigned pk2c(float a, float b) {
    union { bf16x2 v; unsigned u; } c;
    c.v = bf16x2{(__bf16)a, (__bf16)b};
    return c.u;
}
__device__ __forceinline__ unsigned pkbb(__bf16 a, __bf16 b) {
    union { bf16x2 v; unsigned u; } c;
    c.v = bf16x2{a, b};
    return c.u;
}

// ---------------------------------------------------------------------------
// Kernel 1 (merged): blocks 0..255   : pair bias -> fp32 MFMA-C-fragment layout
//                    blocks 256..271 : wq/wk/wv/wg fragment prep (bf16)
//                    blocks 272..275 : wo B-fragment prep (bf16)
// bias32 layout: off(h,i,j) = h*65536 + jc*8192 + w*2048 + (jt*4+it)*256 + l*4 + r
//   where w=i>>6, it=(i>>4)&3, lm=i&15; jc=j>>5, jt=(j>>4)&1, lq=(j>>2)&3, r=j&3,
//   l=lq*16+lm.  log2e folded in (exp2 path).
// ---------------------------------------------------------------------------
__global__ __launch_bounds__(256) void biasprep_kernel(
    const float* __restrict__ z, const float* __restrict__ lnb_s,
    const float* __restrict__ lnb_b, const float* __restrict__ wb,
    const float* __restrict__ wq, const float* __restrict__ wk,
    const float* __restrict__ wv, const float* __restrict__ wg,
    const float* __restrict__ wo,
    float* __restrict__ bias32, unsigned short* __restrict__ wprep,
    unsigned short* __restrict__ wofrag)
{
    const int b = blockIdx.x;
    const int t = threadIdx.x;
    if (b < 256) {
        // ---- bias: block = one i, threads = j. Coalesced z stage via LDS. ----
        __shared__ float zL[256 * 33];               // pitch 33: conflict-free rows
        const float4* src = (const float4*)(z + (size_t)b * NJ * NC);
#pragma unroll
        for (int k = 0; k < 8; ++k) {
            int idx = t + 256 * k;                   // float4 index
            float4 v = src[idx];
            int f = idx * 4;
            int j = f >> 5, c = f & 31;
            zL[j * 33 + c]     = v.x; zL[j * 33 + c + 1] = v.y;
            zL[j * 33 + c + 2] = v.z; zL[j * 33 + c + 3] = v.w;
        }
        __syncthreads();

        float x[NC];
#pragma unroll
        for (int c = 0; c < NC; ++c) x[c] = zL[t * 33 + c];
        float mu = 0.f;
#pragma unroll
        for (int c = 0; c < NC; ++c) mu += x[c];
        mu *= (1.0f / NC);
        float var = 0.f;
#pragma unroll
        for (int c = 0; c < NC; ++c) { float d = x[c] - mu; var += d * d; }
        var *= (1.0f / NC);
        float rs = rsqrtf(var + LN_EPS);
        float acc[NH];
#pragma unroll
        for (int h = 0; h < NH; ++h) acc[h] = 0.f;
#pragma unroll
        for (int c = 0; c < NC; ++c) {
            float xn = (x[c] - mu) * rs * lnb_s[c] + lnb_b[c];
#pragma unroll
            for (int h = 0; h < NH; ++h) acc[h] += xn * wb[c * NH + h];
        }
        const int i = b;
        const int w_ = i >> 6, it = (i >> 4) & 3, lm = i & 15;
        const int jc = t >> 5, jt = (t >> 4) & 1, lq = (t >> 2) & 3, r = t & 3;
        const int base = jc * 8192 + w_ * 2048 + (jt * 4 + it) * 256
                       + (lq * 16 + lm) * 4 + r;
#pragma unroll
        for (int h = 0; h < NH; ++h)
            bias32[h * 65536 + base] = acc[h] * LOG2E;
    } else if (b < 272) {
        // ---- QKVG weight fragments: wprep[t8*8+e] = Wp[(8*lq+e)*256 + 32h+16ct+lm]
        int g = (b - 256) * 256 + t;                 // 0..4095
        int p  = g >> 10;
        int h  = (g >> 7) & 7;
        int ct = (g >> 6) & 1;
        int l  = g & 63;
        const float* W = (p == 0) ? wq : (p == 1) ? wk : (p == 2) ? wv : wg;
        float scale = (p == 0) ? QSCALE * LOG2E : (p == 3) ? LOG2E : 1.0f;
        int col = 32 * h + 16 * ct + (l & 15);
        int r0  = 8 * (l >> 4);
        float v[8];
#pragma unroll
        for (int e = 0; e < 8; ++e) v[e] = W[(r0 + e) * 256 + col] * scale;
        uint4 u;
        u.x = pk2c(v[0], v[1]); u.y = pk2c(v[2], v[3]);
        u.z = pk2c(v[4], v[5]); u.w = pk2c(v[6], v[7]);
        *(uint4*)&wprep[g * 8] = u;
    } else {
        // ---- wo B-fragments: wofrag[((kt*2+nt)*64+l)*8+e] = wo[(kt*32+8lq+e)*32+nt*16+lm]
        int g = (b - 272) * 256 + t;                 // 0..1023
        int tile = g >> 6;                           // kt*2+nt
        int l = g & 63;
        int kt = tile >> 1, nt = tile & 1;
        int r0 = kt * 32 + 8 * (l >> 4);
        int col = nt * 16 + (l & 15);
        float v[8];
#pragma unroll
        for (int e = 0; e < 8; ++e) v[e] = wo[(r0 + e) * 32 + col];
        uint4 u;
        u.x = pk2c(v[0], v[1]); u.y = pk2c(v[2], v[3]);
        u.z = pk2c(v[4], v[5]); u.w = pk2c(v[6], v[7]);
        *(uint4*)&wofrag[g * 8] = u;
    }
}

// ---------------------------------------------------------------------------
// Kernel 2: all-MFMA fused attention, software-pipelined j-loop.
// Block = (s,h), 256 thr = 4 waves, wave owns 64 i (= its 64 j for K/V).
// Pipeline: K frags hoisted to regs; bias C-tiles prefetched 1 jc ahead;
// P double-buffered (QPX / Pb1); PV lagged 1 jc; V prefetched 1 jc ahead.
// Gate recomputed in epilogue from retained X frags (keeps loop regs < 256).
// LDS: QPX 20K | Pb1 20K | Kt 20K | Vt2 17K = 78.8 KB -> 2 blocks/CU.
// ---------------------------------------------------------------------------
__global__ __launch_bounds__(256, 2) void attn_kernel(
    const float* __restrict__ m, const float* __restrict__ ln_s,
    const float* __restrict__ ln_b,
    const unsigned short* __restrict__ wprep,
    const float* __restrict__ bias32,
    unsigned short* __restrict__ attn16)
{
    __shared__ unsigned short QPX[256 * 40];     // Xs -> Q^T rows -> P buf 0
    __shared__ unsigned short Pb1[256 * 40];     // P buf 1
    __shared__ unsigned short Kt[256 * 40];      // K rows [j][c]
    __shared__ unsigned short Vt2[32 * 272];     // V^T [c][j]

    const int t = threadIdx.x;
    const int h = blockIdx.x & 7;
    const int s = blockIdx.x >> 3;
    const int l = t & 63, w = t >> 6;
    const int lm = l & 15, lq = l >> 4;
    const int ibase = w * 64;
    const floatx4 zero = {0.f, 0.f, 0.f, 0.f};

    // ---- Phase 1: LN(m[s][t]) -> QPX row t (bf16). Wave-private rows. ----
    {
        const float4* mr = (const float4*)(m + ((size_t)s * NI + t) * NC);
        float x[NC];
#pragma unroll
        for (int k = 0; k < 8; ++k) {
            float4 v = mr[k];
            x[4*k] = v.x; x[4*k+1] = v.y; x[4*k+2] = v.z; x[4*k+3] = v.w;
        }
        float mu = 0.f;
#pragma unroll
        for (int c = 0; c < NC; ++c) mu += x[c];
        mu *= (1.0f / NC);
        float var = 0.f;
#pragma unroll
        for (int c = 0; c < NC; ++c) { float d = x[c] - mu; var += d * d; }
        var *= (1.0f / NC);
        float rs = rsqrtf(var + LN_EPS);
#pragma unroll
        for (int k = 0; k < 4; ++k) {
            uint4 u;
            u.x = pk2c((x[8*k+0]-mu)*rs*ln_s[8*k+0]+ln_b[8*k+0],
                       (x[8*k+1]-mu)*rs*ln_s[8*k+1]+ln_b[8*k+1]);
            u.y = pk2c((x[8*k+2]-mu)*rs*ln_s[8*k+2]+ln_b[8*k+2],
                       (x[8*k+3]-mu)*rs*ln_s[8*k+3]+ln_b[8*k+3]);
            u.z = pk2c((x[8*k+4]-mu)*rs*ln_s[8*k+4]+ln_b[8*k+4],
                       (x[8*k+5]-mu)*rs*ln_s[8*k+5]+ln_b[8*k+5]);
            u.w = pk2c((x[8*k+6]-mu)*rs*ln_s[8*k+6]+ln_b[8*k+6],
                       (x[8*k+7]-mu)*rs*ln_s[8*k+7]+ln_b[8*k+7]);
            *(uint4*)&QPX[t * 40 + 8 * k] = u;
        }
    }
    // no barrier: wave-private rows

    // ---- Phase 2: MFMA projections (Q/K/V). Gate deferred to epilogue. ----
    const unsigned short* wp = wprep + ((size_t)h * 128 + l) * 8;
    bf16x8 wfQ[2], wfK[2], wfV[2];
#pragma unroll
    for (int ct = 0; ct < 2; ++ct) {
        wfQ[ct] = *(const bf16x8*)&wp[(0 * 1024 + ct * 64) * 8];
        wfK[ct] = *(const bf16x8*)&wp[(1 * 1024 + ct * 64) * 8];
        wfV[ct] = *(const bf16x8*)&wp[(2 * 1024 + ct * 64) * 8];
    }
    bf16x8 Xb[4];                                 // retained for epilogue gate
#pragma unroll
    for (int it = 0; it < 4; ++it)
        Xb[it] = *(const bf16x8*)&QPX[(ibase + it * 16 + lm) * 40 + lq * 8];
    // QPX (Xs) now dead for this wave -> reuse for Q^T

    // Q^T rows [i][c]  (D[c][i]: lane lm = i, regs = 4 consecutive c)
#pragma unroll
    for (int it = 0; it < 4; ++it)
#pragma unroll
        for (int ct = 0; ct < 2; ++ct) {
            floatx4 d = __builtin_amdgcn_mfma_f32_16x16x32_bf16(wfQ[ct], Xb[it], zero, 0, 0, 0);
            uint2 u; u.x = pk2c(d[0], d[1]); u.y = pk2c(d[2], d[3]);
            *(uint2*)&QPX[(ibase + it * 16 + lm) * 40 + ct * 16 + lq * 4] = u;
        }
    // K^T rows [j][c]
#pragma unroll
    for (int it = 0; it < 4; ++it)
#pragma unroll
        for (int ct = 0; ct < 2; ++ct) {
            floatx4 d = __builtin_amdgcn_mfma_f32_16x16x32_bf16(wfK[ct], Xb[it], zero, 0, 0, 0);
            uint2 u; u.x = pk2c(d[0], d[1]); u.y = pk2c(d[2], d[3]);
            *(uint2*)&Kt[(ibase + it * 16 + lm) * 40 + ct * 16 + lq * 4] = u;
        }
    // V -> Vt2 [c][j]  (D[j][c]: lane lm = c, regs = 4 consecutive j)
#pragma unroll
    for (int jt = 0; jt < 4; ++jt)
#pragma unroll
        for (int ct = 0; ct < 2; ++ct) {
            floatx4 d = __builtin_amdgcn_mfma_f32_16x16x32_bf16(Xb[jt], wfV[ct], zero, 0, 0, 0);
            uint2 u; u.x = pk2c(d[0], d[1]); u.y = pk2c(d[2], d[3]);
            *(uint2*)&Vt2[(ct * 16 + lm) * 272 + ibase + jt * 16 + lq * 4] = u;
        }

    // Hoist own Q^T B-frags before the barrier (wave-private rows)
    bf16x8 Qb[4];
#pragma unroll
    for (int it = 0; it < 4; ++it)
        Qb[it] = *(const bf16x8*)&QPX[(ibase + it * 16 + lm) * 40 + lq * 8];

    __syncthreads();   // Kt / Vt2 visible to all waves (the only barrier)

    // Hoist ALL K B-frags to registers (64 VGPR) — no LDS reads at loop head
    bf16x8 Kf[8][2];
#pragma unroll
    for (int jcx = 0; jcx < 8; ++jcx) {
        Kf[jcx][0] = *(const bf16x8*)&Kt[(jcx * 32 + lm) * 40 + lq * 8];
        Kf[jcx][1] = *(const bf16x8*)&Kt[(jcx * 32 + 16 + lm) * 40 + lq * 8];
    }

    floatx4 accO[2][4];
#pragma unroll
    for (int ct = 0; ct < 2; ++ct)
#pragma unroll
        for (int it = 0; it < 4; ++it) accO[ct][it] = zero;
    float lsum[4] = {0.f, 0.f, 0.f, 0.f};

    const float* bptr = bias32 + (size_t)h * 65536 + w * 2048 + l * 4;

    // Prologue: bias C-tiles for jc=0
    floatx4 Cb[8];
#pragma unroll
    for (int q = 0; q < 8; ++q) Cb[q] = *(const floatx4*)(bptr + q * 256);

    bf16x8 Vp0, Vp1;   // V frags belonging to the pending (lagged) PV

    // ---- Phase 3: pipelined j-loop, 32 j per iteration, PV lagged 1 jc ----
#pragma unroll
    for (int jc = 0; jc < 8; ++jc) {
        const int j0 = jc * 32;
        // V frags for THIS jc (consumed by PV at jc+1 / drain)
        bf16x8 Vc0 = *(const bf16x8*)&Vt2[lm * 272 + j0 + lq * 8];
        bf16x8 Vc1 = *(const bf16x8*)&Vt2[(16 + lm) * 272 + j0 + lq * 8];

        // QK with bias as C-operand (K frags in regs -> no wait)
        floatx4 S[2][4];
#pragma unroll
        for (int jt = 0; jt < 2; ++jt)
#pragma unroll
            for (int it = 0; it < 4; ++it)
                S[jt][it] = __builtin_amdgcn_mfma_f32_16x16x32_bf16(
                    Kf[jc][jt], Qb[it], Cb[jt * 4 + it], 0, 0, 0);

        // Cb dead now — prefetch next jc's bias tiles (hides L2 latency)
        if (jc < 7) {
            const float* bn = bptr + (jc + 1) * 8192;
#pragma unroll
            for (int q = 0; q < 8; ++q) Cb[q] = *(const floatx4*)(bn + q * 256);
        }

        unsigned short* Pc = (jc & 1) ? Pb1 : QPX;
        const unsigned short* Pp = (jc & 1) ? QPX : Pb1;

        // Read previous P frags early (latency overlapped by exp below)
        bf16x8 Pfrag[4];
        if (jc > 0) {
#pragma unroll
            for (int it = 0; it < 4; ++it)
                Pfrag[it] = *(const bf16x8*)&Pp[(ibase + it * 16 + lm) * 40 + lq * 8];
        }

        // exp2, bf16-consistent denom, pack P rows into current buffer
#pragma unroll
        for (int jt = 0; jt < 2; ++jt)
#pragma unroll
            for (int it = 0; it < 4; ++it) {
                __bf16 p0 = (__bf16)fexp2(S[jt][it][0]);
                __bf16 p1 = (__bf16)fexp2(S[jt][it][1]);
                __bf16 p2 = (__bf16)fexp2(S[jt][it][2]);
                __bf16 p3 = (__bf16)fexp2(S[jt][it][3]);
                lsum[it] += ((float)p0 + (float)p1) + ((float)p2 + (float)p3);
                uint2 u; u.x = pkbb(p0, p1); u.y = pkbb(p2, p3);
                *(uint2*)&Pc[(ibase + it * 16 + lm) * 40 + jt * 16 + lq * 4] = u;
            }

        // Lagged PV: O^T[c][i] += V^T(jc-1) x P^T(jc-1)
        if (jc > 0) {
#pragma unroll
            for (int it = 0; it < 4; ++it) {
                accO[0][it] = __builtin_amdgcn_mfma_f32_16x16x32_bf16(Vp0, Pfrag[it], accO[0][it], 0, 0, 0);
                accO[1][it] = __builtin_amdgcn_mfma_f32_16x16x32_bf16(Vp1, Pfrag[it], accO[1][it], 0, 0, 0);
            }
        }
        Vp0 = Vc0; Vp1 = Vc1;
    }
    // Drain: PV for jc=7 (written to Pb1)
    {
#pragma unroll
        for (int it = 0; it < 4; ++it) {
            bf16x8 Pfrag = *(const bf16x8*)&Pb1[(ibase + it * 16 + lm) * 40 + lq * 8];
            accO[0][it] = __builtin_amdgcn_mfma_f32_16x16x32_bf16(Vp0, Pfrag, accO[0][it], 0, 0, 0);
            accO[1][it] = __builtin_amdgcn_mfma_f32_16x16x32_bf16(Vp1, Pfrag, accO[1][it], 0, 0, 0);
        }
    }

    // ---- Epilogue: gate recompute (fp32), denom, store bf16 attn16[s][i][d] ----
    float gt[2][4][4];
    {
        bf16x8 wfG0 = *(const bf16x8*)&wp[(3 * 1024 + 0 * 64) * 8];
        bf16x8 wfG1 = *(const bf16x8*)&wp[(3 * 1024 + 1 * 64) * 8];
#pragma unroll
        for (int it = 0; it < 4; ++it) {
            floatx4 d0 = __builtin_amdgcn_mfma_f32_16x16x32_bf16(wfG0, Xb[it], zero, 0, 0, 0);
            floatx4 d1 = __builtin_amdgcn_mfma_f32_16x16x32_bf16(wfG1, Xb[it], zero, 0, 0, 0);
#pragma unroll
            for (int r = 0; r < 4; ++r) {
                gt[0][it][r] = frcp(1.0f + fexp2(-d0[r]));
                gt[1][it][r] = frcp(1.0f + fexp2(-d1[r]));
            }
        }
    }
    float inv[4];
#pragma unroll
    for (int it = 0; it < 4; ++it) {
        float v = lsum[it];
        v += __shfl_xor(v, 16, 64);
        v += __shfl_xor(v, 32, 64);
        inv[it] = frcp(v);
    }
#pragma unroll
    for (int it = 0; it < 4; ++it) {
        const size_t rowb = ((size_t)s * NI + ibase + it * 16 + lm) * 256 + h * 32;
#pragma unroll
        for (int ct = 0; ct < 2; ++ct) {
            float o0 = accO[ct][it][0] * inv[it] * gt[ct][it][0];
            float o1 = accO[ct][it][1] * inv[it] * gt[ct][it][1];
            float o2 = accO[ct][it][2] * inv[it] * gt[ct][it][2];
            float o3 = accO[ct][it][3] * inv[it] * gt[ct][it][3];
            uint2 u; u.x = pk2c(o0, o1); u.y = pk2c(o2, o3);
            *(uint2*)&attn16[rowb + ct * 16 + lq * 4] = u;
        }
    }
}

// ---------------------------------------------------------------------------
// Kernel 3: MFMA output projection. out = attn16(32768x256) @ wo(256x32) + bo
// Block = 256 thr = 4 waves; wave = 32 rows. A from attn16 (b128, coalesced),
// B from wofrag. D[m=i][n=c'] -> fp32 coalesced row stores.
// ---------------------------------------------------------------------------
__global__ __launch_bounds__(256) void proj_kernel(
    const unsigned short* __restrict__ attn16,
    const unsigned short* __restrict__ wofrag,
    const float* __restrict__ bo, float* __restrict__ out)
{
    const int t = threadIdx.x;
    const int l = t & 63, w = t >> 6;
    const int lm = l & 15, lq = l >> 4;
    const int row0 = blockIdx.x * 128 + w * 32;
    const floatx4 zero = {0.f, 0.f, 0.f, 0.f};

    floatx4 acc[2][2];
#pragma unroll
    for (int it = 0; it < 2; ++it)
#pragma unroll
        for (int nt = 0; nt < 2; ++nt) acc[it][nt] = zero;

#pragma unroll 2
    for (int kt = 0; kt < 8; ++kt) {
        bf16x8 a0 = *(const bf16x8*)&attn16[(size_t)(row0 + lm) * 256 + kt * 32 + lq * 8];
        bf16x8 a1 = *(const bf16x8*)&attn16[(size_t)(row0 + 16 + lm) * 256 + kt * 32 + lq * 8];
        bf16x8 b0 = *(const bf16x8*)&wofrag[((kt * 2 + 0) * 64 + l) * 8];
        bf16x8 b1 = *(const bf16x8*)&wofrag[((kt * 2 + 1) * 64 + l) * 8];
        acc[0][0] = __builtin_amdgcn_mfma_f32_16x16x32_bf16(a0, b0, acc[0][0], 0, 0, 0);
        acc[0][1] = __builtin_amdgcn_mfma_f32_16x16x32_bf16(a0, b1, acc[0][1], 0, 0, 0);
        acc[1][0] = __builtin_amdgcn_mfma_f32_16x16x32_bf16(a1, b0, acc[1][0], 0, 0, 0);
        acc[1][1] = __builtin_amdgcn_mfma_f32_16x16x32_bf16(a1, b1, acc[1][1], 0, 0, 0);
    }

    float bov[2] = {bo[lm], bo[16 + lm]};
#pragma unroll
    for (int it = 0; it < 2; ++it)
#pragma unroll
        for (int nt = 0; nt < 2; ++nt)
#pragma unroll
            for (int r = 0; r < 4; ++r)
                out[(size_t)(row0 + it * 16 + lq * 4 + r) * NC + nt * 16 + lm]
                    = acc[it][nt][r] + bov[nt];
}

// ---------------------------------------------------------------------------
extern "C" void kernel_launch(void* const* d_in, const int* in_sizes, int n_in,
                              void* d_out, int out_size, void* d_ws, size_t ws_size,
                              hipStream_t stream) {
    const float* m     = (const float*)d_in[0];
    const float* z     = (const float*)d_in[1];
    const float* ln_s  = (const float*)d_in[2];
    const float* ln_b  = (const float*)d_in[3];
    const float* lnb_s = (const float*)d_in[4];
    const float* lnb_b = (const float*)d_in[5];
    const float* wq    = (const float*)d_in[6];
    const float* wk    = (const float*)d_in[7];
    const float* wv    = (const float*)d_in[8];
    const float* wb    = (const float*)d_in[9];
    const float* wg    = (const float*)d_in[10];
    const float* wo    = (const float*)d_in[11];
    const float* bo    = (const float*)d_in[12];
    float* out = (float*)d_out;

    // ws: bias32 2 MB | wprep 64 KB | wofrag 16 KB | attn16 16.78 MB
    float* bias32 = (float*)d_ws;
    unsigned short* wprep  = (unsigned short*)((char*)d_ws + (2u << 20));
    unsigned short* wofrag = (unsigned short*)((char*)d_ws + (2u << 20) + 65536);
    unsigned short* attn16 = (unsigned short*)((char*)d_ws + (2u << 20) + 65536 + 16384);

    biasprep_kernel<<<276, 256, 0, stream>>>(z, lnb_s, lnb_b, wb, wq, wk, wv, wg,
                                             wo, bias32, wprep, wofrag);
    attn_kernel<<<NS * NH, 256, 0, stream>>>(m, ln_s, ln_b, wprep, bias32, attn16);
    proj_kernel<<<(NS * NI) / 128, 256, 0, stream>>>(attn16, wofrag, bo, out);
}

// Round 6
// 128.625 us; speedup vs baseline: 1.3871x; 1.3871x over previous
//
#include <hip/hip_runtime.h>

constexpr int NC = 32;    // channels C
constexpr int NH = 8;     // heads
constexpr int NS = 128;   // s
constexpr int NI = 256;   // i (q rows)
constexpr int NJ = 256;   // j (kv rows)
constexpr float LN_EPS = 1e-5f;
constexpr float QSCALE = 0.17677669529663687f;   // C^-0.5
constexpr float LOG2E  = 1.4426950408889634f;

typedef __bf16 bf16x8 __attribute__((ext_vector_type(8)));
typedef __bf16 bf16x2 __attribute__((ext_vector_type(2)));
typedef float floatx4 __attribute__((ext_vector_type(4)));

__device__ __forceinline__ float fexp2(float x) {
#if __has_builtin(__builtin_amdgcn_exp2f)
    return __builtin_amdgcn_exp2f(x);
#else
    return exp2f(x);
#endif
}
__device__ __forceinline__ float frcp(float x) {
#if __has_builtin(__builtin_amdgcn_rcpf)
    return __builtin_amdgcn_rcpf(x);
#else
    return 1.0f / x;
#endif
}
// HW bf16 pack (v_cvt_pk_bf16_f32 on gfx950), RNE
__device__ __forceinline__ unsigned pk2c(float a, float b) {
    union { bf16x2 v; unsigned u; } c;
    c.v = bf16x2{(__bf16)a, (__bf16)b};
    return c.u;
}
__device__ __forceinline__ unsigned pkbb(__bf16 a, __bf16 b) {
    union { bf16x2 v; unsigned u; } c;
    c.v = bf16x2{a, b};
    return c.u;
}

// ---------------------------------------------------------------------------
// Kernel 1 (merged): blocks 0..255   : pair bias -> fp32 MFMA-C-fragment layout
//                    blocks 256..271 : wq/wk/wv/wg fragment prep (bf16)
//                    blocks 272..275 : wo B-fragment prep (bf16)
// bias32 layout: off(h,i,j) = h*65536 + jc*8192 + w*2048 + (jt*4+it)*256 + l*4 + r
//   where w=i>>6, it=(i>>4)&3, lm=i&15; jc=j>>5, jt=(j>>4)&1, lq=(j>>2)&3, r=j&3,
//   l=lq*16+lm.  log2e folded in (exp2 path).
// ---------------------------------------------------------------------------
__global__ __launch_bounds__(256) void biasprep_kernel(
    const float* __restrict__ z, const float* __restrict__ lnb_s,
    const float* __restrict__ lnb_b, const float* __restrict__ wb,
    const float* __restrict__ wq, const float* __restrict__ wk,
    const float* __restrict__ wv, const float* __restrict__ wg,
    const float* __restrict__ wo,
    float* __restrict__ bias32, unsigned short* __restrict__ wprep,
    unsigned short* __restrict__ wofrag)
{
    const int b = blockIdx.x;
    const int t = threadIdx.x;
    if (b < 256) {
        // ---- bias: block = one i, threads = j. Coalesced z stage via LDS. ----
        __shared__ float zL[256 * 33];               // pitch 33: conflict-free rows
        const float4* src = (const float4*)(z + (size_t)b * NJ * NC);
#pragma unroll
        for (int k = 0; k < 8; ++k) {
            int idx = t + 256 * k;                   // float4 index
            float4 v = src[idx];
            int f = idx * 4;
            int j = f >> 5, c = f & 31;
            zL[j * 33 + c]     = v.x; zL[j * 33 + c + 1] = v.y;
            zL[j * 33 + c + 2] = v.z; zL[j * 33 + c + 3] = v.w;
        }
        __syncthreads();

        float x[NC];
#pragma unroll
        for (int c = 0; c < NC; ++c) x[c] = zL[t * 33 + c];
        float mu = 0.f;
#pragma unroll
        for (int c = 0; c < NC; ++c) mu += x[c];
        mu *= (1.0f / NC);
        float var = 0.f;
#pragma unroll
        for (int c = 0; c < NC; ++c) { float d = x[c] - mu; var += d * d; }
        var *= (1.0f / NC);
        float rs = rsqrtf(var + LN_EPS);
        float acc[NH];
#pragma unroll
        for (int h = 0; h < NH; ++h) acc[h] = 0.f;
#pragma unroll
        for (int c = 0; c < NC; ++c) {
            float xn = (x[c] - mu) * rs * lnb_s[c] + lnb_b[c];
#pragma unroll
            for (int h = 0; h < NH; ++h) acc[h] += xn * wb[c * NH + h];
        }
        const int i = b;
        const int w_ = i >> 6, it = (i >> 4) & 3, lm = i & 15;
        const int jc = t >> 5, jt = (t >> 4) & 1, lq = (t >> 2) & 3, r = t & 3;
        const int base = jc * 8192 + w_ * 2048 + (jt * 4 + it) * 256
                       + (lq * 16 + lm) * 4 + r;
#pragma unroll
        for (int h = 0; h < NH; ++h)
            bias32[h * 65536 + base] = acc[h] * LOG2E;
    } else if (b < 272) {
        // ---- QKVG weight fragments: wprep[t8*8+e] = Wp[(8*lq+e)*256 + 32h+16ct+lm]
        int g = (b - 256) * 256 + t;                 // 0..4095
        int p  = g >> 10;
        int h  = (g >> 7) & 7;
        int ct = (g >> 6) & 1;
        int l  = g & 63;
        const float* W = (p == 0) ? wq : (p == 1) ? wk : (p == 2) ? wv : wg;
        float scale = (p == 0) ? QSCALE * LOG2E : (p == 3) ? LOG2E : 1.0f;
        int col = 32 * h + 16 * ct + (l & 15);
        int r0  = 8 * (l >> 4);
        float v[8];
#pragma unroll
        for (int e = 0; e < 8; ++e) v[e] = W[(r0 + e) * 256 + col] * scale;
        uint4 u;
        u.x = pk2c(v[0], v[1]); u.y = pk2c(v[2], v[3]);
        u.z = pk2c(v[4], v[5]); u.w = pk2c(v[6], v[7]);
        *(uint4*)&wprep[g * 8] = u;
    } else {
        // ---- wo B-fragments: wofrag[((kt*2+nt)*64+l)*8+e] = wo[(kt*32+8lq+e)*32+nt*16+lm]
        int g = (b - 272) * 256 + t;                 // 0..1023
        int tile = g >> 6;                           // kt*2+nt
        int l = g & 63;
        int kt = tile >> 1, nt = tile & 1;
        int r0 = kt * 32 + 8 * (l >> 4);
        int col = nt * 16 + (l & 15);
        float v[8];
#pragma unroll
        for (int e = 0; e < 8; ++e) v[e] = wo[(r0 + e) * 32 + col];
        uint4 u;
        u.x = pk2c(v[0], v[1]); u.y = pk2c(v[2], v[3]);
        u.z = pk2c(v[4], v[5]); u.w = pk2c(v[6], v[7]);
        *(uint4*)&wofrag[g * 8] = u;
    }
}

// ---------------------------------------------------------------------------
// Kernel 2: all-MFMA fused attention. R4 structure + P double-buffer with
// PV lagged one jc (the ONLY pipelining kept from R5 — R5's K/bias register
// hoists spilled at the 128-VGPR allocation: FETCH +51MB, WRITE +83MB).
// Gate computed in the epilogue from retained X frags (−16 loop-live regs).
// Block = (s,h), 256 thr = 4 waves, wave owns 64 i (= its 64 j for K/V).
// LDS: QPX 20K | Pb1 20K | Kt 20K | Vt2 17K = 78.8 KB -> 2 blocks/CU.
// ---------------------------------------------------------------------------
__global__ __launch_bounds__(256, 2) void attn_kernel(
    const float* __restrict__ m, const float* __restrict__ ln_s,
    const float* __restrict__ ln_b,
    const unsigned short* __restrict__ wprep,
    const float* __restrict__ bias32,
    unsigned short* __restrict__ attn16)
{
    __shared__ unsigned short QPX[256 * 40];     // Xs -> Q^T rows -> P buf 0
    __shared__ unsigned short Pb1[256 * 40];     // P buf 1
    __shared__ unsigned short Kt[256 * 40];      // K rows [j][c]
    __shared__ unsigned short Vt2[32 * 272];     // V^T [c][j]

    const int t = threadIdx.x;
    const int h = blockIdx.x & 7;
    const int s = blockIdx.x >> 3;
    const int l = t & 63, w = t >> 6;
    const int lm = l & 15, lq = l >> 4;
    const int ibase = w * 64;
    const floatx4 zero = {0.f, 0.f, 0.f, 0.f};

    // ---- Phase 1: LN(m[s][t]) -> QPX row t (bf16). Wave-private rows. ----
    {
        const float4* mr = (const float4*)(m + ((size_t)s * NI + t) * NC);
        float x[NC];
#pragma unroll
        for (int k = 0; k < 8; ++k) {
            float4 v = mr[k];
            x[4*k] = v.x; x[4*k+1] = v.y; x[4*k+2] = v.z; x[4*k+3] = v.w;
        }
        float mu = 0.f;
#pragma unroll
        for (int c = 0; c < NC; ++c) mu += x[c];
        mu *= (1.0f / NC);
        float var = 0.f;
#pragma unroll
        for (int c = 0; c < NC; ++c) { float d = x[c] - mu; var += d * d; }
        var *= (1.0f / NC);
        float rs = rsqrtf(var + LN_EPS);
#pragma unroll
        for (int k = 0; k < 4; ++k) {
            uint4 u;
            u.x = pk2c((x[8*k+0]-mu)*rs*ln_s[8*k+0]+ln_b[8*k+0],
                       (x[8*k+1]-mu)*rs*ln_s[8*k+1]+ln_b[8*k+1]);
            u.y = pk2c((x[8*k+2]-mu)*rs*ln_s[8*k+2]+ln_b[8*k+2],
                       (x[8*k+3]-mu)*rs*ln_s[8*k+3]+ln_b[8*k+3]);
            u.z = pk2c((x[8*k+4]-mu)*rs*ln_s[8*k+4]+ln_b[8*k+4],
                       (x[8*k+5]-mu)*rs*ln_s[8*k+5]+ln_b[8*k+5]);
            u.w = pk2c((x[8*k+6]-mu)*rs*ln_s[8*k+6]+ln_b[8*k+6],
                       (x[8*k+7]-mu)*rs*ln_s[8*k+7]+ln_b[8*k+7]);
            *(uint4*)&QPX[t * 40 + 8 * k] = u;
        }
    }
    // no barrier: wave-private rows

    // ---- Phase 2: MFMA projections (Q/K/V). Gate deferred to epilogue. ----
    const unsigned short* wp = wprep + ((size_t)h * 128 + l) * 8;
    bf16x8 wfQ[2], wfK[2], wfV[2];
#pragma unroll
    for (int ct = 0; ct < 2; ++ct) {
        wfQ[ct] = *(const bf16x8*)&wp[(0 * 1024 + ct * 64) * 8];
        wfK[ct] = *(const bf16x8*)&wp[(1 * 1024 + ct * 64) * 8];
        wfV[ct] = *(const bf16x8*)&wp[(2 * 1024 + ct * 64) * 8];
    }
    bf16x8 Xb[4];                                 // retained for epilogue gate
#pragma unroll
    for (int it = 0; it < 4; ++it)
        Xb[it] = *(const bf16x8*)&QPX[(ibase + it * 16 + lm) * 40 + lq * 8];
    // QPX (Xs) now dead for this wave -> reuse for Q^T

    // Q^T rows [i][c]  (D[c][i]: lane lm = i, regs = 4 consecutive c)
#pragma unroll
    for (int it = 0; it < 4; ++it)
#pragma unroll
        for (int ct = 0; ct < 2; ++ct) {
            floatx4 d = __builtin_amdgcn_mfma_f32_16x16x32_bf16(wfQ[ct], Xb[it], zero, 0, 0, 0);
            uint2 u; u.x = pk2c(d[0], d[1]); u.y = pk2c(d[2], d[3]);
            *(uint2*)&QPX[(ibase + it * 16 + lm) * 40 + ct * 16 + lq * 4] = u;
        }
    // K^T rows [j][c]
#pragma unroll
    for (int it = 0; it < 4; ++it)
#pragma unroll
        for (int ct = 0; ct < 2; ++ct) {
            floatx4 d = __builtin_amdgcn_mfma_f32_16x16x32_bf16(wfK[ct], Xb[it], zero, 0, 0, 0);
            uint2 u; u.x = pk2c(d[0], d[1]); u.y = pk2c(d[2], d[3]);
            *(uint2*)&Kt[(ibase + it * 16 + lm) * 40 + ct * 16 + lq * 4] = u;
        }
    // V -> Vt2 [c][j]  (D[j][c]: lane lm = c, regs = 4 consecutive j)
#pragma unroll
    for (int jt = 0; jt < 4; ++jt)
#pragma unroll
        for (int ct = 0; ct < 2; ++ct) {
            floatx4 d = __builtin_amdgcn_mfma_f32_16x16x32_bf16(Xb[jt], wfV[ct], zero, 0, 0, 0);
            uint2 u; u.x = pk2c(d[0], d[1]); u.y = pk2c(d[2], d[3]);
            *(uint2*)&Vt2[(ct * 16 + lm) * 272 + ibase + jt * 16 + lq * 4] = u;
        }

    // Hoist own Q^T B-frags before the barrier (wave-private rows)
    bf16x8 Qb[4];
#pragma unroll
    for (int it = 0; it < 4; ++it)
        Qb[it] = *(const bf16x8*)&QPX[(ibase + it * 16 + lm) * 40 + lq * 8];

    __syncthreads();   // Kt / Vt2 visible to all waves (the only barrier)

    floatx4 accO[2][4];
#pragma unroll
    for (int ct = 0; ct < 2; ++ct)
#pragma unroll
        for (int it = 0; it < 4; ++it) accO[ct][it] = zero;
    float lsum[4] = {0.f, 0.f, 0.f, 0.f};

    const float* bptr = bias32 + (size_t)h * 65536 + w * 2048 + l * 4;
    bf16x8 Vp0, Vp1;   // V frags of the pending (lagged) PV

    // ---- Phase 3: j-loop, 32 j / iter; P dbuf, PV lagged one jc ----
#pragma unroll 2
    for (int jc = 0; jc < 8; ++jc) {
        unsigned short* Pc = (jc & 1) ? Pb1 : QPX;
        const unsigned short* Pp = (jc & 1) ? QPX : Pb1;

        // Read previous P frags FIRST — latency hides under bias/QK below
        bf16x8 Pfrag[4];
        if (jc > 0) {
#pragma unroll
            for (int it = 0; it < 4; ++it)
                Pfrag[it] = *(const bf16x8*)&Pp[(ibase + it * 16 + lm) * 40 + lq * 8];
        }

        const int j0 = jc * 32;
        bf16x8 Ka0 = *(const bf16x8*)&Kt[(j0 + lm) * 40 + lq * 8];
        bf16x8 Ka1 = *(const bf16x8*)&Kt[(j0 + 16 + lm) * 40 + lq * 8];
        bf16x8 Va0 = *(const bf16x8*)&Vt2[lm * 272 + j0 + lq * 8];
        bf16x8 Va1 = *(const bf16x8*)&Vt2[(16 + lm) * 272 + j0 + lq * 8];

        // QK with bias C-operand
        const float* bj = bptr + jc * 8192;
        floatx4 S[2][4];
#pragma unroll
        for (int jt = 0; jt < 2; ++jt) {
            bf16x8 Ka = jt ? Ka1 : Ka0;
#pragma unroll
            for (int it = 0; it < 4; ++it) {
                floatx4 C = *(const floatx4*)(bj + (jt * 4 + it) * 256);
                S[jt][it] = __builtin_amdgcn_mfma_f32_16x16x32_bf16(Ka, Qb[it], C, 0, 0, 0);
            }
        }

        // Lagged PV (covers QK output latency; Pfrag dies before exp)
        if (jc > 0) {
#pragma unroll
            for (int it = 0; it < 4; ++it) {
                accO[0][it] = __builtin_amdgcn_mfma_f32_16x16x32_bf16(Vp0, Pfrag[it], accO[0][it], 0, 0, 0);
                accO[1][it] = __builtin_amdgcn_mfma_f32_16x16x32_bf16(Vp1, Pfrag[it], accO[1][it], 0, 0, 0);
            }
        }

        // exp2, bf16-consistent denom, pack P rows into current buffer
#pragma unroll
        for (int jt = 0; jt < 2; ++jt)
#pragma unroll
            for (int it = 0; it < 4; ++it) {
                __bf16 p0 = (__bf16)fexp2(S[jt][it][0]);
                __bf16 p1 = (__bf16)fexp2(S[jt][it][1]);
                __bf16 p2 = (__bf16)fexp2(S[jt][it][2]);
                __bf16 p3 = (__bf16)fexp2(S[jt][it][3]);
                lsum[it] += ((float)p0 + (float)p1) + ((float)p2 + (float)p3);
                uint2 u; u.x = pkbb(p0, p1); u.y = pkbb(p2, p3);
                *(uint2*)&Pc[(ibase + it * 16 + lm) * 40 + jt * 16 + lq * 4] = u;
            }

        Vp0 = Va0; Vp1 = Va1;
    }
    // Drain: PV for jc=7 (its P went to Pb1)
#pragma unroll
    for (int it = 0; it < 4; ++it) {
        bf16x8 Pfrag = *(const bf16x8*)&Pb1[(ibase + it * 16 + lm) * 40 + lq * 8];
        accO[0][it] = __builtin_amdgcn_mfma_f32_16x16x32_bf16(Vp0, Pfrag, accO[0][it], 0, 0, 0);
        accO[1][it] = __builtin_amdgcn_mfma_f32_16x16x32_bf16(Vp1, Pfrag, accO[1][it], 0, 0, 0);
    }

    // ---- Epilogue: gate from retained Xb, denom, store attn16[s][i][d] ----
    float gt[2][4][4];
    {
        bf16x8 wfG0 = *(const bf16x8*)&wp[(3 * 1024 + 0 * 64) * 8];
        bf16x8 wfG1 = *(const bf16x8*)&wp[(3 * 1024 + 1 * 64) * 8];
#pragma unroll
        for (int it = 0; it < 4; ++it) {
            floatx4 d0 = __builtin_amdgcn_mfma_f32_16x16x32_bf16(wfG0, Xb[it], zero, 0, 0, 0);
            floatx4 d1 = __builtin_amdgcn_mfma_f32_16x16x32_bf16(wfG1, Xb[it], zero, 0, 0, 0);
#pragma unroll
            for (int r = 0; r < 4; ++r) {
                gt[0][it][r] = frcp(1.0f + fexp2(-d0[r]));
                gt[1][it][r] = frcp(1.0f + fexp2(-d1[r]));
            }
        }
    }
    float inv[4];
#pragma unroll
    for (int it = 0; it < 4; ++it) {
        float v = lsum[it];
        v += __shfl_xor(v, 16, 64);
        v += __shfl_xor(v, 32, 64);
        inv[it] = frcp(v);
    }
#pragma unroll
    for (int it = 0; it < 4; ++it) {
        const size_t rowb = ((size_t)s * NI + ibase + it * 16 + lm) * 256 + h * 32;
#pragma unroll
        for (int ct = 0; ct < 2; ++ct) {
            float o0 = accO[ct][it][0] * inv[it] * gt[ct][it][0];
            float o1 = accO[ct][it][1] * inv[it] * gt[ct][it][1];
            float o2 = accO[ct][it][2] * inv[it] * gt[ct][it][2];
            float o3 = accO[ct][it][3] * inv[it] * gt[ct][it][3];
            uint2 u; u.x = pk2c(o0, o1); u.y = pk2c(o2, o3);
            *(uint2*)&attn16[rowb + ct * 16 + lq * 4] = u;
        }
    }
}

// ---------------------------------------------------------------------------
// Kernel 3: MFMA output projection. out = attn16(32768x256) @ wo(256x32) + bo
// Block = 256 thr = 4 waves; wave = 32 rows. A from attn16 (b128, coalesced),
// B from wofrag. D[m=i][n=c'] -> fp32 coalesced row stores.
// ---------------------------------------------------------------------------
__global__ __launch_bounds__(256) void proj_kernel(
    const unsigned short* __restrict__ attn16,
    const unsigned short* __restrict__ wofrag,
    const float* __restrict__ bo, float* __restrict__ out)
{
    const int t = threadIdx.x;
    const int l = t & 63, w = t >> 6;
    const int lm = l & 15, lq = l >> 4;
    const int row0 = blockIdx.x * 128 + w * 32;
    const floatx4 zero = {0.f, 0.f, 0.f, 0.f};

    floatx4 acc[2][2];
#pragma unroll
    for (int it = 0; it < 2; ++it)
#pragma unroll
        for (int nt = 0; nt < 2; ++nt) acc[it][nt] = zero;

#pragma unroll 2
    for (int kt = 0; kt < 8; ++kt) {
        bf16x8 a0 = *(const bf16x8*)&attn16[(size_t)(row0 + lm) * 256 + kt * 32 + lq * 8];
        bf16x8 a1 = *(const bf16x8*)&attn16[(size_t)(row0 + 16 + lm) * 256 + kt * 32 + lq * 8];
        bf16x8 b0 = *(const bf16x8*)&wofrag[((kt * 2 + 0) * 64 + l) * 8];
        bf16x8 b1 = *(const bf16x8*)&wofrag[((kt * 2 + 1) * 64 + l) * 8];
        acc[0][0] = __builtin_amdgcn_mfma_f32_16x16x32_bf16(a0, b0, acc[0][0], 0, 0, 0);
        acc[0][1] = __builtin_amdgcn_mfma_f32_16x16x32_bf16(a0, b1, acc[0][1], 0, 0, 0);
        acc[1][0] = __builtin_amdgcn_mfma_f32_16x16x32_bf16(a1, b0, acc[1][0], 0, 0, 0);
        acc[1][1] = __builtin_amdgcn_mfma_f32_16x16x32_bf16(a1, b1, acc[1][1], 0, 0, 0);
    }

    float bov[2] = {bo[lm], bo[16 + lm]};
#pragma unroll
    for (int it = 0; it < 2; ++it)
#pragma unroll
        for (int nt = 0; nt < 2; ++nt)
#pragma unroll
            for (int r = 0; r < 4; ++r)
                out[(size_t)(row0 + it * 16 + lq * 4 + r) * NC + nt * 16 + lm]
                    = acc[it][nt][r] + bov[nt];
}

// ---------------------------------------------------------------------------
extern "C" void kernel_launch(void* const* d_in, const int* in_sizes, int n_in,
                              void* d_out, int out_size, void* d_ws, size_t ws_size,
                              hipStream_t stream) {
    const float* m     = (const float*)d_in[0];
    const float* z     = (const float*)d_in[1];
    const float* ln_s  = (const float*)d_in[2];
    const float* ln_b  = (const float*)d_in[3];
    const float* lnb_s = (const float*)d_in[4];
    const float* lnb_b = (const float*)d_in[5];
    const float* wq    = (const float*)d_in[6];
    const float* wk    = (const float*)d_in[7];
    const float* wv    = (const float*)d_in[8];
    const float* wb    = (const float*)d_in[9];
    const float* wg    = (const float*)d_in[10];
    const float* wo    = (const float*)d_in[11];
    const float* bo    = (const float*)d_in[12];
    float* out = (float*)d_out;

    // ws: bias32 2 MB | wprep 64 KB | wofrag 16 KB | attn16 16.78 MB
    float* bias32 = (float*)d_ws;
    unsigned short* wprep  = (unsigned short*)((char*)d_ws + (2u << 20));
    unsigned short* wofrag = (unsigned short*)((char*)d_ws + (2u << 20) + 65536);
    unsigned short* attn16 = (unsigned short*)((char*)d_ws + (2u << 20) + 65536 + 16384);

    biasprep_kernel<<<276, 256, 0, stream>>>(z, lnb_s, lnb_b, wb, wq, wk, wv, wg,
                                             wo, bias32, wprep, wofrag);
    attn_kernel<<<NS * NH, 256, 0, stream>>>(m, ln_s, ln_b, wprep, bias32, attn16);
    proj_kernel<<<(NS * NI) / 128, 256, 0, stream>>>(attn16, wofrag, bo, out);
}

// Round 7
// 120.199 us; speedup vs baseline: 1.4843x; 1.0701x over previous
//
#include <hip/hip_runtime.h>

constexpr int NC = 32;    // channels C
constexpr int NH = 8;     // heads
constexpr int NS = 128;   // s
constexpr int NI = 256;   // i (q rows)
constexpr int NJ = 256;   // j (kv rows)
constexpr float LN_EPS = 1e-5f;
constexpr float QSCALE = 0.17677669529663687f;   // C^-0.5
constexpr float LOG2E  = 1.4426950408889634f;

typedef __bf16 bf16x8 __attribute__((ext_vector_type(8)));
typedef __bf16 bf16x2 __attribute__((ext_vector_type(2)));
typedef float floatx4 __attribute__((ext_vector_type(4)));

__device__ __forceinline__ float fexp2(float x) {
#if __has_builtin(__builtin_amdgcn_exp2f)
    return __builtin_amdgcn_exp2f(x);
#else
    return exp2f(x);
#endif
}
__device__ __forceinline__ float frcp(float x) {
#if __has_builtin(__builtin_amdgcn_rcpf)
    return __builtin_amdgcn_rcpf(x);
#else
    return 1.0f / x;
#endif
}
// HW bf16 pack (v_cvt_pk_bf16_f32 on gfx950), RNE
__device__ __forceinline__ unsigned pk2c(float a, float b) {
    union { bf16x2 v; unsigned u; } c;
    c.v = bf16x2{(__bf16)a, (__bf16)b};
    return c.u;
}
__device__ __forceinline__ unsigned pkbb(__bf16 a, __bf16 b) {
    union { bf16x2 v; unsigned u; } c;
    c.v = bf16x2{a, b};
    return c.u;
}

// XOR-swizzled LDS offsets (shorts). Rows of 32 shorts (4 x 16B chunks):
// phys_chunk = chunk ^ ((row>>1)&3)  -> <=2-way banks on all b128 reads.
__device__ __forceinline__ int qkOff(int row, int chunk) {
    return row * 32 + ((chunk ^ ((row >> 1) & 3)) << 3);
}
// V^T rows of 256 shorts (32 chunks): phys_chunk = chunk ^ (c&7).
__device__ __forceinline__ int vOff(int c, int chunk) {
    return c * 256 + ((chunk ^ (c & 7)) << 3);
}

// ---------------------------------------------------------------------------
// Kernel 1 (merged): blocks 0..255   : pair bias -> fp32 MFMA-C-fragment layout
//                    blocks 256..271 : wq/wk/wv/wg fragment prep (bf16)
//                    blocks 272..275 : wo B-fragment prep (bf16)
// bias32 layout: off(h,i,j) = h*65536 + jc*8192 + w*2048 + (jt*4+it)*256 + l*4 + r
//   log2e folded in (exp2 path).
// ---------------------------------------------------------------------------
__global__ __launch_bounds__(256) void biasprep_kernel(
    const float* __restrict__ z, const float* __restrict__ lnb_s,
    const float* __restrict__ lnb_b, const float* __restrict__ wb,
    const float* __restrict__ wq, const float* __restrict__ wk,
    const float* __restrict__ wv, const float* __restrict__ wg,
    const float* __restrict__ wo,
    float* __restrict__ bias32, unsigned short* __restrict__ wprep,
    unsigned short* __restrict__ wofrag)
{
    const int b = blockIdx.x;
    const int t = threadIdx.x;
    if (b < 256) {
        // ---- bias: block = one i, threads = j. Coalesced z stage via LDS. ----
        __shared__ float zL[256 * 33];               // pitch 33: conflict-free rows
        const float4* src = (const float4*)(z + (size_t)b * NJ * NC);
#pragma unroll
        for (int k = 0; k < 8; ++k) {
            int idx = t + 256 * k;                   // float4 index
            float4 v = src[idx];
            int f = idx * 4;
            int j = f >> 5, c = f & 31;
            zL[j * 33 + c]     = v.x; zL[j * 33 + c + 1] = v.y;
            zL[j * 33 + c + 2] = v.z; zL[j * 33 + c + 3] = v.w;
        }
        __syncthreads();

        float x[NC];
#pragma unroll
        for (int c = 0; c < NC; ++c) x[c] = zL[t * 33 + c];
        float mu = 0.f;
#pragma unroll
        for (int c = 0; c < NC; ++c) mu += x[c];
        mu *= (1.0f / NC);
        float var = 0.f;
#pragma unroll
        for (int c = 0; c < NC; ++c) { float d = x[c] - mu; var += d * d; }
        var *= (1.0f / NC);
        float rs = rsqrtf(var + LN_EPS);
        float acc[NH];
#pragma unroll
        for (int h = 0; h < NH; ++h) acc[h] = 0.f;
#pragma unroll
        for (int c = 0; c < NC; ++c) {
            float xn = (x[c] - mu) * rs * lnb_s[c] + lnb_b[c];
#pragma unroll
            for (int h = 0; h < NH; ++h) acc[h] += xn * wb[c * NH + h];
        }
        const int i = b;
        const int w_ = i >> 6, it = (i >> 4) & 3, lm = i & 15;
        const int jc = t >> 5, jt = (t >> 4) & 1, lq = (t >> 2) & 3, r = t & 3;
        const int base = jc * 8192 + w_ * 2048 + (jt * 4 + it) * 256
                       + (lq * 16 + lm) * 4 + r;
#pragma unroll
        for (int h = 0; h < NH; ++h)
            bias32[h * 65536 + base] = acc[h] * LOG2E;
    } else if (b < 272) {
        // ---- QKVG weight fragments ----
        int g = (b - 256) * 256 + t;                 // 0..4095
        int p  = g >> 10;
        int h  = (g >> 7) & 7;
        int ct = (g >> 6) & 1;
        int l  = g & 63;
        const float* W = (p == 0) ? wq : (p == 1) ? wk : (p == 2) ? wv : wg;
        float scale = (p == 0) ? QSCALE * LOG2E : (p == 3) ? LOG2E : 1.0f;
        int col = 32 * h + 16 * ct + (l & 15);
        int r0  = 8 * (l >> 4);
        float v[8];
#pragma unroll
        for (int e = 0; e < 8; ++e) v[e] = W[(r0 + e) * 256 + col] * scale;
        uint4 u;
        u.x = pk2c(v[0], v[1]); u.y = pk2c(v[2], v[3]);
        u.z = pk2c(v[4], v[5]); u.w = pk2c(v[6], v[7]);
        *(uint4*)&wprep[g * 8] = u;
    } else {
        // ---- wo B-fragments ----
        int g = (b - 272) * 256 + t;                 // 0..1023
        int tile = g >> 6;                           // kt*2+nt
        int l = g & 63;
        int kt = tile >> 1, nt = tile & 1;
        int r0 = kt * 32 + 8 * (l >> 4);
        int col = nt * 16 + (l & 15);
        float v[8];
#pragma unroll
        for (int e = 0; e < 8; ++e) v[e] = wo[(r0 + e) * 32 + col];
        uint4 u;
        u.x = pk2c(v[0], v[1]); u.y = pk2c(v[2], v[3]);
        u.z = pk2c(v[4], v[5]); u.w = pk2c(v[6], v[7]);
        *(uint4*)&wofrag[g * 8] = u;
    }
}

// ---------------------------------------------------------------------------
// Kernel 2: all-MFMA fused attention, 48 KB LDS -> 3 blocks/CU (12 waves).
// XOR-swizzled LDS (no padding). Denominator via ones-MFMA (idle MFMA pipe,
// bf16-consistent with P, no shfl reduce). Single P buffer (dbuf was neutral
// in R6). Per-jt processing keeps loop-live VGPRs ~<160 (R5 spill lesson).
// LDS: QPX (X -> Q^T -> P) 16K | Kt 16K | Vt 16K = 48 KB.
// ---------------------------------------------------------------------------
__global__ __launch_bounds__(256, 3) void attn_kernel(
    const float* __restrict__ m, const float* __restrict__ ln_s,
    const float* __restrict__ ln_b,
    const unsigned short* __restrict__ wprep,
    const float* __restrict__ bias32,
    unsigned short* __restrict__ attn16)
{
    __shared__ unsigned short QPX[256 * 32];     // X rows -> Q^T rows -> P rows
    __shared__ unsigned short Kt[256 * 32];      // K rows [j][c]
    __shared__ unsigned short Vt[32 * 256];      // V^T [c][j]

    const int t = threadIdx.x;
    const int h = blockIdx.x & 7;
    const int s = blockIdx.x >> 3;
    const int l = t & 63, w = t >> 6;
    const int lm = l & 15, lq = l >> 4;
    const int ibase = w * 64;
    const floatx4 zero = {0.f, 0.f, 0.f, 0.f};

    // ---- Phase 1: LN(m[s][t]) -> QPX row t (bf16, swizzled). Wave-private. ----
    {
        const float4* mr = (const float4*)(m + ((size_t)s * NI + t) * NC);
        float x[NC];
#pragma unroll
        for (int k = 0; k < 8; ++k) {
            float4 v = mr[k];
            x[4*k] = v.x; x[4*k+1] = v.y; x[4*k+2] = v.z; x[4*k+3] = v.w;
        }
        float mu = 0.f;
#pragma unroll
        for (int c = 0; c < NC; ++c) mu += x[c];
        mu *= (1.0f / NC);
        float var = 0.f;
#pragma unroll
        for (int c = 0; c < NC; ++c) { float d = x[c] - mu; var += d * d; }
        var *= (1.0f / NC);
        float rs = rsqrtf(var + LN_EPS);
#pragma unroll
        for (int k = 0; k < 4; ++k) {
            uint4 u;
            u.x = pk2c((x[8*k+0]-mu)*rs*ln_s[8*k+0]+ln_b[8*k+0],
                       (x[8*k+1]-mu)*rs*ln_s[8*k+1]+ln_b[8*k+1]);
            u.y = pk2c((x[8*k+2]-mu)*rs*ln_s[8*k+2]+ln_b[8*k+2],
                       (x[8*k+3]-mu)*rs*ln_s[8*k+3]+ln_b[8*k+3]);
            u.z = pk2c((x[8*k+4]-mu)*rs*ln_s[8*k+4]+ln_b[8*k+4],
                       (x[8*k+5]-mu)*rs*ln_s[8*k+5]+ln_b[8*k+5]);
            u.w = pk2c((x[8*k+6]-mu)*rs*ln_s[8*k+6]+ln_b[8*k+6],
                       (x[8*k+7]-mu)*rs*ln_s[8*k+7]+ln_b[8*k+7]);
            *(uint4*)&QPX[qkOff(t, k)] = u;
        }
    }
    // no barrier: wave-private rows

    // ---- Phase 2: MFMA projections (Q/K/V). Gate deferred to epilogue. ----
    const unsigned short* wp = wprep + ((size_t)h * 128 + l) * 8;
    bf16x8 wfQ[2], wfK[2], wfV[2];
#pragma unroll
    for (int ct = 0; ct < 2; ++ct) {
        wfQ[ct] = *(const bf16x8*)&wp[(0 * 1024 + ct * 64) * 8];
        wfK[ct] = *(const bf16x8*)&wp[(1 * 1024 + ct * 64) * 8];
        wfV[ct] = *(const bf16x8*)&wp[(2 * 1024 + ct * 64) * 8];
    }
    bf16x8 Xb[4];                                 // retained for epilogue gate
#pragma unroll
    for (int it = 0; it < 4; ++it)
        Xb[it] = *(const bf16x8*)&QPX[qkOff(ibase + it * 16 + lm, lq)];
    // QPX (X) now dead for this wave -> reuse for Q^T

    // Q^T rows [i][c]  (D[c][i]: lane lm = i, regs = 4 consecutive c)
#pragma unroll
    for (int it = 0; it < 4; ++it)
#pragma unroll
        for (int ct = 0; ct < 2; ++ct) {
            floatx4 d = __builtin_amdgcn_mfma_f32_16x16x32_bf16(wfQ[ct], Xb[it], zero, 0, 0, 0);
            uint2 u; u.x = pk2c(d[0], d[1]); u.y = pk2c(d[2], d[3]);
            int row = ibase + it * 16 + lm;
            *(uint2*)&QPX[qkOff(row, 2 * ct + (lq >> 1)) + (lq & 1) * 4] = u;
        }
    // K^T rows [j][c]
#pragma unroll
    for (int it = 0; it < 4; ++it)
#pragma unroll
        for (int ct = 0; ct < 2; ++ct) {
            floatx4 d = __builtin_amdgcn_mfma_f32_16x16x32_bf16(wfK[ct], Xb[it], zero, 0, 0, 0);
            uint2 u; u.x = pk2c(d[0], d[1]); u.y = pk2c(d[2], d[3]);
            int row = ibase + it * 16 + lm;
            *(uint2*)&Kt[qkOff(row, 2 * ct + (lq >> 1)) + (lq & 1) * 4] = u;
        }
    // V -> Vt [c][j]  (D[j][c']: lane lm = c', regs = 4 consecutive j)
#pragma unroll
    for (int jt = 0; jt < 4; ++jt)
#pragma unroll
        for (int ct = 0; ct < 2; ++ct) {
            floatx4 d = __builtin_amdgcn_mfma_f32_16x16x32_bf16(Xb[jt], wfV[ct], zero, 0, 0, 0);
            uint2 u; u.x = pk2c(d[0], d[1]); u.y = pk2c(d[2], d[3]);
            int c = ct * 16 + lm;
            int chunk = 8 * w + 2 * jt + (lq >> 1);
            *(uint2*)&Vt[vOff(c, chunk) + (lq & 1) * 4] = u;
        }

    // Hoist own Q^T B-frags before the barrier (wave-private rows)
    bf16x8 Qb[4];
#pragma unroll
    for (int it = 0; it < 4; ++it)
        Qb[it] = *(const bf16x8*)&QPX[qkOff(ibase + it * 16 + lm, lq)];

    __syncthreads();   // Kt / Vt visible to all waves (the only barrier)

    floatx4 accO[2][4];
#pragma unroll
    for (int ct = 0; ct < 2; ++ct)
#pragma unroll
        for (int it = 0; it < 4; ++it) accO[ct][it] = zero;
    floatx4 accL[4];                // denominator via ones-MFMA
#pragma unroll
    for (int it = 0; it < 4; ++it) accL[it] = zero;
    bf16x8 ones;
#pragma unroll
    for (int e = 0; e < 8; ++e) ones[e] = (__bf16)1.0f;

    const float* bptr = bias32 + (size_t)h * 65536 + w * 2048 + l * 4;

    // ---- Phase 3: j-loop, 32 j per iteration ----
    for (int jc = 0; jc < 8; ++jc) {
        const int j0 = jc * 32;
        const float* bj = bptr + jc * 8192;

        // S = K x Q^T + bias(C);  p = exp2(S); pack P rows (per-jt: low liveness)
#pragma unroll
        for (int jt = 0; jt < 2; ++jt) {
            bf16x8 Ka = *(const bf16x8*)&Kt[qkOff(j0 + jt * 16 + lm, lq)];
#pragma unroll
            for (int it = 0; it < 4; ++it) {
                floatx4 C = *(const floatx4*)(bj + (jt * 4 + it) * 256);
                floatx4 S = __builtin_amdgcn_mfma_f32_16x16x32_bf16(Ka, Qb[it], C, 0, 0, 0);
                __bf16 p0 = (__bf16)fexp2(S[0]);
                __bf16 p1 = (__bf16)fexp2(S[1]);
                __bf16 p2 = (__bf16)fexp2(S[2]);
                __bf16 p3 = (__bf16)fexp2(S[3]);
                uint2 u; u.x = pkbb(p0, p1); u.y = pkbb(p2, p3);
                int row = ibase + it * 16 + lm;
                *(uint2*)&QPX[qkOff(row, 2 * jt + (lq >> 1)) + (lq & 1) * 4] = u;
            }
        }

        // PV + denominator: O^T[c][i] += V^T x P^T ; L[i] += ones x P^T
        bf16x8 Va0 = *(const bf16x8*)&Vt[vOff(lm, 4 * jc + lq)];
        bf16x8 Va1 = *(const bf16x8*)&Vt[vOff(16 + lm, 4 * jc + lq)];
#pragma unroll
        for (int it = 0; it < 4; ++it) {
            bf16x8 Pb = *(const bf16x8*)&QPX[qkOff(ibase + it * 16 + lm, lq)];
            accO[0][it] = __builtin_amdgcn_mfma_f32_16x16x32_bf16(Va0, Pb, accO[0][it], 0, 0, 0);
            accO[1][it] = __builtin_amdgcn_mfma_f32_16x16x32_bf16(Va1, Pb, accO[1][it], 0, 0, 0);
            accL[it]    = __builtin_amdgcn_mfma_f32_16x16x32_bf16(ones, Pb, accL[it], 0, 0, 0);
        }
    }

    // ---- Epilogue: gate from retained Xb, denom (in-register), store ----
    float gt[2][4][4];
    {
        bf16x8 wfG0 = *(const bf16x8*)&wp[(3 * 1024 + 0 * 64) * 8];
        bf16x8 wfG1 = *(const bf16x8*)&wp[(3 * 1024 + 1 * 64) * 8];
#pragma unroll
        for (int it = 0; it < 4; ++it) {
            floatx4 d0 = __builtin_amdgcn_mfma_f32_16x16x32_bf16(wfG0, Xb[it], zero, 0, 0, 0);
            floatx4 d1 = __builtin_amdgcn_mfma_f32_16x16x32_bf16(wfG1, Xb[it], zero, 0, 0, 0);
#pragma unroll
            for (int r = 0; r < 4; ++r) {
                gt[0][it][r] = frcp(1.0f + fexp2(-d0[r]));
                gt[1][it][r] = frcp(1.0f + fexp2(-d1[r]));
            }
        }
    }
#pragma unroll
    for (int it = 0; it < 4; ++it) {
        const float inv = frcp(accL[it][0]);     // all lanes/regs hold own i's L
        const size_t rowb = ((size_t)s * NI + ibase + it * 16 + lm) * 256 + h * 32;
#pragma unroll
        for (int ct = 0; ct < 2; ++ct) {
            float o0 = accO[ct][it][0] * inv * gt[ct][it][0];
            float o1 = accO[ct][it][1] * inv * gt[ct][it][1];
            float o2 = accO[ct][it][2] * inv * gt[ct][it][2];
            float o3 = accO[ct][it][3] * inv * gt[ct][it][3];
            uint2 u; u.x = pk2c(o0, o1); u.y = pk2c(o2, o3);
            *(uint2*)&attn16[rowb + ct * 16 + lq * 4] = u;
        }
    }
}

// ---------------------------------------------------------------------------
// Kernel 3: MFMA output projection. out = attn16(32768x256) @ wo(256x32) + bo
// ---------------------------------------------------------------------------
__global__ __launch_bounds__(256) void proj_kernel(
    const unsigned short* __restrict__ attn16,
    const unsigned short* __restrict__ wofrag,
    const float* __restrict__ bo, float* __restrict__ out)
{
    const int t = threadIdx.x;
    const int l = t & 63, w = t >> 6;
    const int lm = l & 15, lq = l >> 4;
    const int row0 = blockIdx.x * 128 + w * 32;
    const floatx4 zero = {0.f, 0.f, 0.f, 0.f};

    floatx4 acc[2][2];
#pragma unroll
    for (int it = 0; it < 2; ++it)
#pragma unroll
        for (int nt = 0; nt < 2; ++nt) acc[it][nt] = zero;

#pragma unroll 2
    for (int kt = 0; kt < 8; ++kt) {
        bf16x8 a0 = *(const bf16x8*)&attn16[(size_t)(row0 + lm) * 256 + kt * 32 + lq * 8];
        bf16x8 a1 = *(const bf16x8*)&attn16[(size_t)(row0 + 16 + lm) * 256 + kt * 32 + lq * 8];
        bf16x8 b0 = *(const bf16x8*)&wofrag[((kt * 2 + 0) * 64 + l) * 8];
        bf16x8 b1 = *(const bf16x8*)&wofrag[((kt * 2 + 1) * 64 + l) * 8];
        acc[0][0] = __builtin_amdgcn_mfma_f32_16x16x32_bf16(a0, b0, acc[0][0], 0, 0, 0);
        acc[0][1] = __builtin_amdgcn_mfma_f32_16x16x32_bf16(a0, b1, acc[0][1], 0, 0, 0);
        acc[1][0] = __builtin_amdgcn_mfma_f32_16x16x32_bf16(a1, b0, acc[1][0], 0, 0, 0);
        acc[1][1] = __builtin_amdgcn_mfma_f32_16x16x32_bf16(a1, b1, acc[1][1], 0, 0, 0);
    }

    float bov[2] = {bo[lm], bo[16 + lm]};
#pragma unroll
    for (int it = 0; it < 2; ++it)
#pragma unroll
        for (int nt = 0; nt < 2; ++nt)
#pragma unroll
            for (int r = 0; r < 4; ++r)
                out[(size_t)(row0 + it * 16 + lq * 4 + r) * NC + nt * 16 + lm]
                    = acc[it][nt][r] + bov[nt];
}

// ---------------------------------------------------------------------------
extern "C" void kernel_launch(void* const* d_in, const int* in_sizes, int n_in,
                              void* d_out, int out_size, void* d_ws, size_t ws_size,
                              hipStream_t stream) {
    const float* m     = (const float*)d_in[0];
    const float* z     = (const float*)d_in[1];
    const float* ln_s  = (const float*)d_in[2];
    const float* ln_b  = (const float*)d_in[3];
    const float* lnb_s = (const float*)d_in[4];
    const float* lnb_b = (const float*)d_in[5];
    const float* wq    = (const float*)d_in[6];
    const float* wk    = (const float*)d_in[7];
    const float* wv    = (const float*)d_in[8];
    const float* wb    = (const float*)d_in[9];
    const float* wg    = (const float*)d_in[10];
    const float* wo    = (const float*)d_in[11];
    const float* bo    = (const float*)d_in[12];
    float* out = (float*)d_out;

    // ws: bias32 2 MB | wprep 64 KB | wofrag 16 KB | attn16 16.78 MB
    float* bias32 = (float*)d_ws;
    unsigned short* wprep  = (unsigned short*)((char*)d_ws + (2u << 20));
    unsigned short* wofrag = (unsigned short*)((char*)d_ws + (2u << 20) + 65536);
    unsigned short* attn16 = (unsigned short*)((char*)d_ws + (2u << 20) + 65536 + 16384);

    biasprep_kernel<<<276, 256, 0, stream>>>(z, lnb_s, lnb_b, wb, wq, wk, wv, wg,
                                             wo, bias32, wprep, wofrag);
    attn_kernel<<<NS * NH, 256, 0, stream>>>(m, ln_s, ln_b, wprep, bias32, attn16);
    proj_kernel<<<(NS * NI) / 128, 256, 0, stream>>>(attn16, wofrag, bo, out);
}